// Round 1
// baseline (1303.836 us; speedup 1.0000x reference)
//
#include <hip/hip_runtime.h>

typedef __attribute__((ext_vector_type(8))) short bf16x8;
typedef __attribute__((ext_vector_type(4))) float f32x4;
typedef unsigned short u16;
typedef unsigned int u32;

constexpr int kH   = 2048;   // hidden
constexpr int kI   = 1024;   // intermediate
constexpr int kE   = 32;     // experts
constexpr int kK   = 8;      // experts per token
constexpr int kG   = 8;      // groups
constexpr int kKG  = 4;      // groups kept
constexpr int kCap = 1024;   // capacity
constexpr float kScale = 2.5f;

constexpr int BM = 64, BN = 64, BK = 32;
constexpr int LDT = 40;      // padded LDS row stride (bf16 elems); keeps 16B align

__device__ __forceinline__ u16 f2bf(float f) {
    union { float f; u32 u; } v; v.f = f;
    u32 u = v.u + 0x7FFFu + ((v.u >> 16) & 1u);  // RNE
    return (u16)(u >> 16);
}

// ---------------- gate: sigmoid scores + group-limited top-k routing ----------------
__global__ __launch_bounds__(256) void gate_kernel(
    const float* __restrict__ x, const float* __restrict__ w_gate,
    const float* __restrict__ gbias,
    int* __restrict__ cnt, int* __restrict__ tok_of_slot, float* __restrict__ wt_of_slot)
{
    int tok = blockIdx.x;
    int t = threadIdx.x;
    __shared__ float part[256];
    __shared__ float sc[kE], sb[kE];

    const float* xr = x + (size_t)tok * kH;
    int e = t & 31, c = t >> 5;
    const float* wg = w_gate + e;
    float s = 0.f;
    #pragma unroll 4
    for (int h = c * 256; h < c * 256 + 256; ++h)
        s += xr[h] * wg[(size_t)h * kE];
    part[t] = s;
    __syncthreads();

    if (t < kE) {
        float logit = 0.f;
        #pragma unroll
        for (int cc = 0; cc < 8; ++cc) logit += part[t + 32 * cc];
        float sco = 1.f / (1.f + expf(-logit));
        sc[t] = sco;
        sb[t] = sco + gbias[t];
    }
    __syncthreads();

    if (t == 0) {
        // per-group sum of top-2 (selection scores include bias)
        float gsc[kG];
        for (int g = 0; g < kG; ++g) {
            float m1 = -1e30f, m2 = -1e30f;
            for (int j = 0; j < 4; ++j) {
                float v = sb[g * 4 + j];
                if (v > m1) { m2 = m1; m1 = v; } else if (v > m2) { m2 = v; }
            }
            gsc[g] = m1 + m2;
        }
        // keep top-KG groups (ties -> lower index, matches lax.top_k)
        bool gkeep[kG];
        for (int g = 0; g < kG; ++g) gkeep[g] = false;
        for (int it = 0; it < kKG; ++it) {
            float best = -1e30f; int bi = 0;
            for (int g = 0; g < kG; ++g)
                if (!gkeep[g] && gsc[g] > best) { best = gsc[g]; bi = g; }
            gkeep[bi] = true;
        }
        // top-K experts among kept groups; weights from raw scores
        bool taken[kE];
        for (int i = 0; i < kE; ++i) taken[i] = false;
        int sel[kK]; float selw[kK]; float wsum = 0.f;
        for (int it = 0; it < kK; ++it) {
            float best = -1e30f; int bi = 0;
            for (int i = 0; i < kE; ++i)
                if (gkeep[i >> 2] && !taken[i] && sb[i] > best) { best = sb[i]; bi = i; }
            taken[bi] = true;
            sel[it] = bi; selw[it] = sc[bi]; wsum += sc[bi];
        }
        float scl = kScale / wsum;
        for (int it = 0; it < kK; ++it) {
            int ee = sel[it];
            int slot = atomicAdd(&cnt[ee], 1);
            if (slot < kCap) {
                tok_of_slot[ee * kCap + slot] = tok;
                wt_of_slot[ee * kCap + slot] = selw[it] * scl;
            }
        }
    }
}

// ---------------- GEMM1: act[s,i] = silu(x_s @ w1) * (x_s @ w3), bf16 out ----------------
__global__ __launch_bounds__(256) void gemm1_kernel(
    const float* __restrict__ x, const float* __restrict__ w1, const float* __restrict__ w3,
    const int* __restrict__ tok_of_slot, const int* __restrict__ cnt,
    u16* __restrict__ act)
{
    int e = blockIdx.z;
    int count = cnt[e];
    int m0 = blockIdx.y * BM;
    if (m0 >= count) return;
    int n0 = blockIdx.x * BN;

    __shared__ u16 As[BM][LDT];
    __shared__ u16 B1s[BN][LDT];   // [col][k] (transposed)
    __shared__ u16 B3s[BN][LDT];
    __shared__ int toks[BM];

    int t = threadIdx.x;
    if (t < BM) {
        int sidx = m0 + t;
        toks[t] = (sidx < count) ? tok_of_slot[e * kCap + sidx] : -1;
    }

    int lane = t & 63;
    int wv = t >> 6;        // wave -> 16-wide N sub-block
    int lr = lane & 15;
    int kg = lane >> 4;

    f32x4 accg[4], accu[4];
    #pragma unroll
    for (int i = 0; i < 4; ++i) {
        accg[i] = f32x4{0.f, 0.f, 0.f, 0.f};
        accu[i] = f32x4{0.f, 0.f, 0.f, 0.f};
    }

    const float* w1e = w1 + (size_t)e * kH * kI;
    const float* w3e = w3 + (size_t)e * kH * kI;

    for (int k0 = 0; k0 < kH; k0 += BK) {
        __syncthreads();
        // stage A (gathered x rows), fp32 -> bf16
        #pragma unroll
        for (int rep = 0; rep < 2; ++rep) {
            int f = t + rep * 256;
            int row = f >> 3, kq = f & 7;
            int tk = toks[row];
            float4 v = make_float4(0.f, 0.f, 0.f, 0.f);
            if (tk >= 0) v = *(const float4*)(x + (size_t)tk * kH + k0 + kq * 4);
            ushort4 b; b.x = f2bf(v.x); b.y = f2bf(v.y); b.z = f2bf(v.z); b.w = f2bf(v.w);
            *(ushort4*)&As[row][kq * 4] = b;
        }
        // stage B1/B3 transposed: Bs[col][k] = W[k0+k][n0+col]
        #pragma unroll
        for (int rep = 0; rep < 2; ++rep) {
            int f = t + rep * 256;
            int k = f >> 4, i4 = (f & 15) * 4;
            float4 v1 = *(const float4*)(w1e + (size_t)(k0 + k) * kI + n0 + i4);
            B1s[i4 + 0][k] = f2bf(v1.x); B1s[i4 + 1][k] = f2bf(v1.y);
            B1s[i4 + 2][k] = f2bf(v1.z); B1s[i4 + 3][k] = f2bf(v1.w);
            float4 v3 = *(const float4*)(w3e + (size_t)(k0 + k) * kI + n0 + i4);
            B3s[i4 + 0][k] = f2bf(v3.x); B3s[i4 + 1][k] = f2bf(v3.y);
            B3s[i4 + 2][k] = f2bf(v3.z); B3s[i4 + 3][k] = f2bf(v3.w);
        }
        __syncthreads();

        bf16x8 b1 = *(const bf16x8*)&B1s[wv * 16 + lr][kg * 8];
        bf16x8 b3 = *(const bf16x8*)&B3s[wv * 16 + lr][kg * 8];
        #pragma unroll
        for (int mf = 0; mf < 4; ++mf) {
            bf16x8 a = *(const bf16x8*)&As[mf * 16 + lr][kg * 8];
            accg[mf] = __builtin_amdgcn_mfma_f32_16x16x32_bf16(a, b1, accg[mf], 0, 0, 0);
            accu[mf] = __builtin_amdgcn_mfma_f32_16x16x32_bf16(a, b3, accu[mf], 0, 0, 0);
        }
    }

    // epilogue: act = silu(g) * u   (C/D: col=lane&15, row=(lane>>4)*4+reg)
    int orow = (lane >> 4) * 4;
    u16* actp = act + (size_t)e * kCap * kI;
    #pragma unroll
    for (int mf = 0; mf < 4; ++mf) {
        #pragma unroll
        for (int j = 0; j < 4; ++j) {
            int srow = m0 + mf * 16 + orow + j;
            int icol = n0 + wv * 16 + lr;
            float g = accg[mf][j], u = accu[mf][j];
            float sg = g / (1.f + expf(-g));
            actp[(size_t)srow * kI + icol] = f2bf(sg * u);
        }
    }
}

// ---------------- GEMM2: y = act @ w2; out[tok] += w * y (atomic combine) ----------------
__global__ __launch_bounds__(256) void gemm2_kernel(
    const u16* __restrict__ act, const float* __restrict__ w2,
    const int* __restrict__ tok_of_slot, const float* __restrict__ wt_of_slot,
    const int* __restrict__ cnt, float* __restrict__ out)
{
    int e = blockIdx.z;
    int count = cnt[e];
    int m0 = blockIdx.y * BM;
    if (m0 >= count) return;
    int n0 = blockIdx.x * BN;

    __shared__ u16 As[BM][LDT];
    __shared__ u16 Bs[BN][LDT];
    __shared__ int toks[BM];
    __shared__ float wts[BM];

    int t = threadIdx.x;
    if (t < BM) {
        int sidx = m0 + t;
        toks[t] = (sidx < count) ? tok_of_slot[e * kCap + sidx] : -1;
        wts[t]  = (sidx < count) ? wt_of_slot[e * kCap + sidx] : 0.f;
    }

    int lane = t & 63;
    int wv = t >> 6;
    int lr = lane & 15;
    int kg = lane >> 4;

    f32x4 acc[4];
    #pragma unroll
    for (int i = 0; i < 4; ++i) acc[i] = f32x4{0.f, 0.f, 0.f, 0.f};

    const u16* ae = act + (size_t)e * kCap * kI;
    const float* w2e = w2 + (size_t)e * kI * kH;

    for (int k0 = 0; k0 < kI; k0 += BK) {
        __syncthreads();
        {   // stage A (already bf16): 64 rows x 32 k, 16B per thread
            int row = t >> 2, kq = t & 3;
            uint4 v = *(const uint4*)(ae + (size_t)(m0 + row) * kI + k0 + kq * 8);
            *(uint4*)&As[row][kq * 8] = v;
        }
        #pragma unroll
        for (int rep = 0; rep < 2; ++rep) {
            int f = t + rep * 256;
            int k = f >> 4, i4 = (f & 15) * 4;
            float4 v = *(const float4*)(w2e + (size_t)(k0 + k) * kH + n0 + i4);
            Bs[i4 + 0][k] = f2bf(v.x); Bs[i4 + 1][k] = f2bf(v.y);
            Bs[i4 + 2][k] = f2bf(v.z); Bs[i4 + 3][k] = f2bf(v.w);
        }
        __syncthreads();

        bf16x8 b = *(const bf16x8*)&Bs[wv * 16 + lr][kg * 8];
        #pragma unroll
        for (int mf = 0; mf < 4; ++mf) {
            bf16x8 a = *(const bf16x8*)&As[mf * 16 + lr][kg * 8];
            acc[mf] = __builtin_amdgcn_mfma_f32_16x16x32_bf16(a, b, acc[mf], 0, 0, 0);
        }
    }

    int orow = (lane >> 4) * 4;
    #pragma unroll
    for (int mf = 0; mf < 4; ++mf) {
        #pragma unroll
        for (int j = 0; j < 4; ++j) {
            int sr = mf * 16 + orow + j;
            if (m0 + sr < count) {
                int tk = toks[sr];
                float w = wts[sr];
                atomicAdd(&out[(size_t)tk * kH + n0 + wv * 16 + lr], w * acc[mf][j]);
            }
        }
    }
}

extern "C" void kernel_launch(void* const* d_in, const int* in_sizes, int n_in,
                              void* d_out, int out_size, void* d_ws, size_t ws_size,
                              hipStream_t stream) {
    const float* x      = (const float*)d_in[0];
    const float* w_gate = (const float*)d_in[1];
    const float* gbias  = (const float*)d_in[2];
    const float* w1     = (const float*)d_in[3];
    const float* w3     = (const float*)d_in[4];
    const float* w2     = (const float*)d_in[5];
    float* out = (float*)d_out;

    int ntok = in_sizes[0] / kH;

    char* ws = (char*)d_ws;
    int*   cnt         = (int*)(ws);                                   // 128 B
    int*   tok_of_slot = (int*)(ws + 4096);                            // 128 KB
    float* wt_of_slot  = (float*)(ws + 4096 + kE * kCap * 4);          // 128 KB
    u16*   act         = (u16*)(ws + 4096 + 2 * kE * kCap * 4);        // 64 MB

    hipMemsetAsync(cnt, 0, kE * sizeof(int), stream);
    hipMemsetAsync(d_out, 0, (size_t)out_size * sizeof(float), stream);

    gate_kernel<<<ntok, 256, 0, stream>>>(x, w_gate, gbias, cnt, tok_of_slot, wt_of_slot);

    dim3 g1(kI / BN, kCap / BM, kE);
    gemm1_kernel<<<g1, 256, 0, stream>>>(x, w1, w3, tok_of_slot, cnt, act);

    dim3 g2(kH / BN, kCap / BM, kE);
    gemm2_kernel<<<g2, 256, 0, stream>>>(act, w2, tok_of_slot, wt_of_slot, cnt, out);
}

// Round 2
// 1272.048 us; speedup vs baseline: 1.0250x; 1.0250x over previous
//
#include <hip/hip_runtime.h>

typedef __attribute__((ext_vector_type(8))) short bf16x8;
typedef __attribute__((ext_vector_type(4))) float f32x4;
typedef unsigned short u16;
typedef unsigned int u32;

constexpr int kH   = 2048;   // hidden
constexpr int kI   = 1024;   // intermediate
constexpr int kE   = 32;     // experts
constexpr int kK   = 8;      // experts per token
constexpr int kG   = 8;      // groups
constexpr int kKG  = 4;      // groups kept
constexpr int kCap = 1024;   // capacity
constexpr float kScale = 2.5f;

__device__ __forceinline__ u16 f2bf(float f) {
    union { float f; u32 u; } v; v.f = f;
    u32 u = v.u + 0x7FFFu + ((v.u >> 16) & 1u);  // RNE
    return (u16)(u >> 16);
}
__device__ __forceinline__ u32 pk2(float a, float b) {
    return (u32)f2bf(a) | ((u32)f2bf(b) << 16);
}
// XOR-swizzled element index for a [row][64] bf16 LDS tile (128 B rows).
// Flips bits 3-5 of k with row&7 -> b128 reads/writes conflict-free.
__device__ __forceinline__ int swz(int row, int k) {
    return row * 64 + (k ^ ((row & 7) << 3));
}

// ---------------- gate: sigmoid scores + group-limited top-k routing ----------------
__global__ __launch_bounds__(256) void gate_kernel(
    const float* __restrict__ x, const float* __restrict__ w_gate,
    const float* __restrict__ gbias,
    int* __restrict__ cnt, int* __restrict__ tok_of_slot, float* __restrict__ wt_of_slot)
{
    int tok = blockIdx.x;
    int t = threadIdx.x;
    __shared__ float part[256];
    __shared__ float sc[kE], sb[kE];

    const float* xr = x + (size_t)tok * kH;
    int e = t & 31, c = t >> 5;
    const float* wg = w_gate + e;
    float s = 0.f;
    #pragma unroll 4
    for (int h = c * 256; h < c * 256 + 256; ++h)
        s += xr[h] * wg[(size_t)h * kE];
    part[t] = s;
    __syncthreads();

    if (t < kE) {
        float logit = 0.f;
        #pragma unroll
        for (int cc = 0; cc < 8; ++cc) logit += part[t + 32 * cc];
        float sco = 1.f / (1.f + expf(-logit));
        sc[t] = sco;
        sb[t] = sco + gbias[t];
    }
    __syncthreads();

    if (t == 0) {
        float gsc[kG];
        for (int g = 0; g < kG; ++g) {
            float m1 = -1e30f, m2 = -1e30f;
            for (int j = 0; j < 4; ++j) {
                float v = sb[g * 4 + j];
                if (v > m1) { m2 = m1; m1 = v; } else if (v > m2) { m2 = v; }
            }
            gsc[g] = m1 + m2;
        }
        bool gkeep[kG];
        for (int g = 0; g < kG; ++g) gkeep[g] = false;
        for (int it = 0; it < kKG; ++it) {
            float best = -1e30f; int bi = 0;
            for (int g = 0; g < kG; ++g)
                if (!gkeep[g] && gsc[g] > best) { best = gsc[g]; bi = g; }
            gkeep[bi] = true;
        }
        bool taken[kE];
        for (int i = 0; i < kE; ++i) taken[i] = false;
        int sel[kK]; float selw[kK]; float wsum = 0.f;
        for (int it = 0; it < kK; ++it) {
            float best = -1e30f; int bi = 0;
            for (int i = 0; i < kE; ++i)
                if (gkeep[i >> 2] && !taken[i] && sb[i] > best) { best = sb[i]; bi = i; }
            taken[bi] = true;
            sel[it] = bi; selw[it] = sc[bi]; wsum += sc[bi];
        }
        float scl = kScale / wsum;
        for (int it = 0; it < kK; ++it) {
            int ee = sel[it];
            int slot = atomicAdd(&cnt[ee], 1);
            if (slot < kCap) {
                tok_of_slot[ee * kCap + slot] = tok;
                wt_of_slot[ee * kCap + slot] = selw[it] * scl;
            }
        }
    }
}

// ---------------- GEMM1: act = silu(x@w1) * (x@w3), 128x128x64 tiles ----------------
__global__ __launch_bounds__(256) void gemm1_kernel(
    const float* __restrict__ x, const float* __restrict__ w1g, const float* __restrict__ w3g,
    const int* __restrict__ tok_of_slot, const int* __restrict__ cnt,
    u16* __restrict__ act)
{
    int e = blockIdx.z;
    int count = cnt[e];
    int m0 = blockIdx.y * 128;
    if (m0 >= count) return;
    int n0 = blockIdx.x * 128;

    __shared__ u16 As[128 * 64];
    __shared__ u16 B1s[128 * 64];
    __shared__ u16 B3s[128 * 64];
    __shared__ int toks[128];

    int t = threadIdx.x;
    if (t < 128) {
        int s = m0 + t;
        toks[t] = (s < count) ? tok_of_slot[e * kCap + s] : -1;
    }

    int lane = t & 63;
    int wv = t >> 6;
    int wm = (wv >> 1) * 64;   // wave m-offset in tile
    int wn = (wv & 1) * 64;    // wave n-offset in tile
    int lr = lane & 15;
    int kg = lane >> 4;

    f32x4 accg[4][4], accu[4][4];
    #pragma unroll
    for (int i = 0; i < 4; ++i)
        #pragma unroll
        for (int j = 0; j < 4; ++j) {
            accg[i][j] = f32x4{0.f, 0.f, 0.f, 0.f};
            accu[i][j] = f32x4{0.f, 0.f, 0.f, 0.f};
        }

    const float* w1e = w1g + (size_t)e * kH * kI;
    const float* w3e = w3g + (size_t)e * kH * kI;

    for (int k0 = 0; k0 < kH; k0 += 64) {
        __syncthreads();
        // ---- stage A: gathered x rows, fp32->bf16, b128 writes ----
        #pragma unroll
        for (int r = 0; r < 4; ++r) {
            int f = r * 256 + t;
            int row = f >> 3, k8 = (f & 7) * 8;
            int tk = toks[row];
            float4 v0 = make_float4(0.f, 0.f, 0.f, 0.f), v1 = v0;
            if (tk >= 0) {
                const float* p = x + (size_t)tk * kH + k0 + k8;
                v0 = *(const float4*)p;
                v1 = *(const float4*)(p + 4);
            }
            uint4 w;
            w.x = pk2(v0.x, v0.y); w.y = pk2(v0.z, v0.w);
            w.z = pk2(v1.x, v1.y); w.w = pk2(v1.z, v1.w);
            *(uint4*)&As[swz(row, k8)] = w;
        }
        // ---- stage B1/B3: 4x4 register transpose, packed b64 writes ----
        #pragma unroll
        for (int r = 0; r < 2; ++r) {
            int f = r * 256 + t;
            int bn = (f & 31) * 4, bk = (f >> 5) * 4;
            const float* p1 = w1e + (size_t)(k0 + bk) * kI + n0 + bn;
            const float* p3 = w3e + (size_t)(k0 + bk) * kI + n0 + bn;
            float4 c0 = *(const float4*)p1;
            float4 c1 = *(const float4*)(p1 + kI);
            float4 c2 = *(const float4*)(p1 + 2 * kI);
            float4 c3 = *(const float4*)(p1 + 3 * kI);
            uint2 q;
            q.x = pk2(c0.x, c1.x); q.y = pk2(c2.x, c3.x); *(uint2*)&B1s[swz(bn + 0, bk)] = q;
            q.x = pk2(c0.y, c1.y); q.y = pk2(c2.y, c3.y); *(uint2*)&B1s[swz(bn + 1, bk)] = q;
            q.x = pk2(c0.z, c1.z); q.y = pk2(c2.z, c3.z); *(uint2*)&B1s[swz(bn + 2, bk)] = q;
            q.x = pk2(c0.w, c1.w); q.y = pk2(c2.w, c3.w); *(uint2*)&B1s[swz(bn + 3, bk)] = q;
            c0 = *(const float4*)p3;
            c1 = *(const float4*)(p3 + kI);
            c2 = *(const float4*)(p3 + 2 * kI);
            c3 = *(const float4*)(p3 + 3 * kI);
            q.x = pk2(c0.x, c1.x); q.y = pk2(c2.x, c3.x); *(uint2*)&B3s[swz(bn + 0, bk)] = q;
            q.x = pk2(c0.y, c1.y); q.y = pk2(c2.y, c3.y); *(uint2*)&B3s[swz(bn + 1, bk)] = q;
            q.x = pk2(c0.z, c1.z); q.y = pk2(c2.z, c3.z); *(uint2*)&B3s[swz(bn + 2, bk)] = q;
            q.x = pk2(c0.w, c1.w); q.y = pk2(c2.w, c3.w); *(uint2*)&B3s[swz(bn + 3, bk)] = q;
        }
        __syncthreads();
        // ---- MFMA: 4x4 frags x 2 k-halves x 2 matmuls ----
        #pragma unroll
        for (int h = 0; h < 2; ++h) {
            int kk = h * 32 + kg * 8;
            bf16x8 a[4], b1[4], b3[4];
            #pragma unroll
            for (int i = 0; i < 4; ++i) {
                a[i]  = *(const bf16x8*)&As [swz(wm + i * 16 + lr, kk)];
                b1[i] = *(const bf16x8*)&B1s[swz(wn + i * 16 + lr, kk)];
                b3[i] = *(const bf16x8*)&B3s[swz(wn + i * 16 + lr, kk)];
            }
            #pragma unroll
            for (int mi = 0; mi < 4; ++mi)
                #pragma unroll
                for (int ni = 0; ni < 4; ++ni) {
                    accg[mi][ni] = __builtin_amdgcn_mfma_f32_16x16x32_bf16(a[mi], b1[ni], accg[mi][ni], 0, 0, 0);
                    accu[mi][ni] = __builtin_amdgcn_mfma_f32_16x16x32_bf16(a[mi], b3[ni], accu[mi][ni], 0, 0, 0);
                }
        }
    }

    // epilogue: silu(g)*u -> bf16 act.  C/D: col=lane&15, row=(lane>>4)*4+reg
    u16* actp = act + (size_t)e * kCap * kI;
    #pragma unroll
    for (int mi = 0; mi < 4; ++mi)
        #pragma unroll
        for (int ni = 0; ni < 4; ++ni)
            #pragma unroll
            for (int j = 0; j < 4; ++j) {
                int srow = m0 + wm + mi * 16 + kg * 4 + j;
                int icol = n0 + wn + ni * 16 + lr;
                float g = accg[mi][ni][j], u = accu[mi][ni][j];
                float sg = g / (1.f + __expf(-g));
                actp[(size_t)srow * kI + icol] = f2bf(sg * u);
            }
}

// ---------------- GEMM2: y = act @ w2; out[tok] += w*y ----------------
__global__ __launch_bounds__(256) void gemm2_kernel(
    const u16* __restrict__ act, const float* __restrict__ w2g,
    const int* __restrict__ tok_of_slot, const float* __restrict__ wt_of_slot,
    const int* __restrict__ cnt, float* __restrict__ out)
{
    int e = blockIdx.z;
    int count = cnt[e];
    int m0 = blockIdx.y * 128;
    if (m0 >= count) return;
    int n0 = blockIdx.x * 128;

    __shared__ u16 As[128 * 64];
    __shared__ u16 Bs[128 * 64];
    __shared__ int toks[128];
    __shared__ float wts[128];

    int t = threadIdx.x;
    if (t < 128) {
        int s = m0 + t;
        toks[t] = (s < count) ? tok_of_slot[e * kCap + s] : 0;
        wts[t]  = (s < count) ? wt_of_slot[e * kCap + s] : 0.f;
    }

    int lane = t & 63;
    int wv = t >> 6;
    int wm = (wv >> 1) * 64;
    int wn = (wv & 1) * 64;
    int lr = lane & 15;
    int kg = lane >> 4;

    f32x4 acc[4][4];
    #pragma unroll
    for (int i = 0; i < 4; ++i)
        #pragma unroll
        for (int j = 0; j < 4; ++j) acc[i][j] = f32x4{0.f, 0.f, 0.f, 0.f};

    const u16* ae = act + (size_t)e * kCap * kI;
    const float* w2e = w2g + (size_t)e * kI * kH;

    for (int k0 = 0; k0 < kI; k0 += 64) {
        __syncthreads();
        // ---- stage A: act is already bf16, pure b128 copy ----
        #pragma unroll
        for (int r = 0; r < 4; ++r) {
            int f = r * 256 + t;
            int row = f >> 3, k8 = (f & 7) * 8;
            uint4 v = *(const uint4*)(ae + (size_t)(m0 + row) * kI + k0 + k8);
            *(uint4*)&As[swz(row, k8)] = v;
        }
        // ---- stage B: w2 4x4 register transpose ----
        #pragma unroll
        for (int r = 0; r < 2; ++r) {
            int f = r * 256 + t;
            int bn = (f & 31) * 4, bk = (f >> 5) * 4;
            const float* p = w2e + (size_t)(k0 + bk) * kH + n0 + bn;
            float4 c0 = *(const float4*)p;
            float4 c1 = *(const float4*)(p + kH);
            float4 c2 = *(const float4*)(p + 2 * kH);
            float4 c3 = *(const float4*)(p + 3 * kH);
            uint2 q;
            q.x = pk2(c0.x, c1.x); q.y = pk2(c2.x, c3.x); *(uint2*)&Bs[swz(bn + 0, bk)] = q;
            q.x = pk2(c0.y, c1.y); q.y = pk2(c2.y, c3.y); *(uint2*)&Bs[swz(bn + 1, bk)] = q;
            q.x = pk2(c0.z, c1.z); q.y = pk2(c2.z, c3.z); *(uint2*)&Bs[swz(bn + 2, bk)] = q;
            q.x = pk2(c0.w, c1.w); q.y = pk2(c2.w, c3.w); *(uint2*)&Bs[swz(bn + 3, bk)] = q;
        }
        __syncthreads();
        #pragma unroll
        for (int h = 0; h < 2; ++h) {
            int kk = h * 32 + kg * 8;
            bf16x8 a[4], b[4];
            #pragma unroll
            for (int i = 0; i < 4; ++i) {
                a[i] = *(const bf16x8*)&As[swz(wm + i * 16 + lr, kk)];
                b[i] = *(const bf16x8*)&Bs[swz(wn + i * 16 + lr, kk)];
            }
            #pragma unroll
            for (int mi = 0; mi < 4; ++mi)
                #pragma unroll
                for (int ni = 0; ni < 4; ++ni)
                    acc[mi][ni] = __builtin_amdgcn_mfma_f32_16x16x32_bf16(a[mi], b[ni], acc[mi][ni], 0, 0, 0);
        }
    }

    #pragma unroll
    for (int mi = 0; mi < 4; ++mi)
        #pragma unroll
        for (int ni = 0; ni < 4; ++ni)
            #pragma unroll
            for (int j = 0; j < 4; ++j) {
                int sr = wm + mi * 16 + kg * 4 + j;
                if (m0 + sr < count) {
                    atomicAdd(&out[(size_t)toks[sr] * kH + n0 + wn + ni * 16 + lr],
                              wts[sr] * acc[mi][ni][j]);
                }
            }
}

extern "C" void kernel_launch(void* const* d_in, const int* in_sizes, int n_in,
                              void* d_out, int out_size, void* d_ws, size_t ws_size,
                              hipStream_t stream) {
    const float* x      = (const float*)d_in[0];
    const float* w_gate = (const float*)d_in[1];
    const float* gbias  = (const float*)d_in[2];
    const float* w1     = (const float*)d_in[3];
    const float* w3     = (const float*)d_in[4];
    const float* w2     = (const float*)d_in[5];
    float* out = (float*)d_out;

    int ntok = in_sizes[0] / kH;

    char* ws = (char*)d_ws;
    int*   cnt         = (int*)(ws);
    int*   tok_of_slot = (int*)(ws + 4096);
    float* wt_of_slot  = (float*)(ws + 4096 + kE * kCap * 4);
    u16*   act         = (u16*)(ws + 4096 + 2 * kE * kCap * 4);   // 64 MB

    hipMemsetAsync(cnt, 0, kE * sizeof(int), stream);
    hipMemsetAsync(d_out, 0, (size_t)out_size * sizeof(float), stream);

    gate_kernel<<<ntok, 256, 0, stream>>>(x, w_gate, gbias, cnt, tok_of_slot, wt_of_slot);

    dim3 g1(kI / 128, kCap / 128, kE);
    gemm1_kernel<<<g1, 256, 0, stream>>>(x, w1, w3, tok_of_slot, cnt, act);

    dim3 g2(kH / 128, kCap / 128, kE);
    gemm2_kernel<<<g2, 256, 0, stream>>>(act, w2, tok_of_slot, wt_of_slot, cnt, out);
}

// Round 3
// 829.354 us; speedup vs baseline: 1.5721x; 1.5338x over previous
//
#include <hip/hip_runtime.h>

typedef __attribute__((ext_vector_type(8))) short bf16x8;
typedef __attribute__((ext_vector_type(4))) float f32x4;
typedef unsigned short u16;
typedef unsigned int u32;

constexpr int kH   = 2048;   // hidden
constexpr int kI   = 1024;   // intermediate
constexpr int kE   = 32;     // experts
constexpr int kK   = 8;      // experts per token
constexpr int kG   = 8;      // groups
constexpr int kKG  = 4;      // groups kept
constexpr int kCap = 1024;   // capacity
constexpr float kScale = 2.5f;

__device__ __forceinline__ u16 f2bf(float f) {
    union { float f; u32 u; } v; v.f = f;
    u32 u = v.u + 0x7FFFu + ((v.u >> 16) & 1u);  // RNE
    return (u16)(u >> 16);
}
__device__ __forceinline__ u32 pk2(float a, float b) {
    return (u32)f2bf(a) | ((u32)f2bf(b) << 16);
}
// XOR-swizzled element index for a [row][64] bf16 LDS tile (128 B rows).
// XOR of k bits 3-5 with (row ^ row>>3): b128 frag reads stay 2-way (free),
// 4-consecutive-row transpose writes spread across all 32 banks.
__device__ __forceinline__ int swz(int row, int k) {
    return row * 64 + (k ^ ((((row >> 3) ^ row) & 7) << 3));
}

// ---------------- gate: sigmoid scores + group-limited top-k routing ----------------
__global__ __launch_bounds__(256) void gate_kernel(
    const float* __restrict__ x, const float* __restrict__ w_gate,
    const float* __restrict__ gbias,
    int* __restrict__ cnt, int* __restrict__ tok_of_slot, float* __restrict__ wt_of_slot)
{
    int tok = blockIdx.x;
    int t = threadIdx.x;
    __shared__ float part[256];
    __shared__ float sc[kE], sb[kE];

    const float* xr = x + (size_t)tok * kH;
    int e = t & 31, c = t >> 5;
    const float* wg = w_gate + e;
    float s = 0.f;
    #pragma unroll 4
    for (int h = c * 256; h < c * 256 + 256; ++h)
        s += xr[h] * wg[(size_t)h * kE];
    part[t] = s;
    __syncthreads();

    if (t < kE) {
        float logit = 0.f;
        #pragma unroll
        for (int cc = 0; cc < 8; ++cc) logit += part[t + 32 * cc];
        float sco = 1.f / (1.f + expf(-logit));
        sc[t] = sco;
        sb[t] = sco + gbias[t];
    }
    __syncthreads();

    if (t == 0) {
        float gsc[kG];
        for (int g = 0; g < kG; ++g) {
            float m1 = -1e30f, m2 = -1e30f;
            for (int j = 0; j < 4; ++j) {
                float v = sb[g * 4 + j];
                if (v > m1) { m2 = m1; m1 = v; } else if (v > m2) { m2 = v; }
            }
            gsc[g] = m1 + m2;
        }
        bool gkeep[kG];
        for (int g = 0; g < kG; ++g) gkeep[g] = false;
        for (int it = 0; it < kKG; ++it) {
            float best = -1e30f; int bi = 0;
            for (int g = 0; g < kG; ++g)
                if (!gkeep[g] && gsc[g] > best) { best = gsc[g]; bi = g; }
            gkeep[bi] = true;
        }
        bool taken[kE];
        for (int i = 0; i < kE; ++i) taken[i] = false;
        int sel[kK]; float selw[kK]; float wsum = 0.f;
        for (int it = 0; it < kK; ++it) {
            float best = -1e30f; int bi = 0;
            for (int i = 0; i < kE; ++i)
                if (gkeep[i >> 2] && !taken[i] && sb[i] > best) { best = sb[i]; bi = i; }
            taken[bi] = true;
            sel[it] = bi; selw[it] = sc[bi]; wsum += sc[bi];
        }
        float scl = kScale / wsum;
        for (int it = 0; it < kK; ++it) {
            int ee = sel[it];
            int slot = atomicAdd(&cnt[ee], 1);
            if (slot < kCap) {
                tok_of_slot[ee * kCap + slot] = tok;
                wt_of_slot[ee * kCap + slot] = selw[it] * scl;
            }
        }
    }
}

// ---------------- GEMM1: act = silu(x@w1)*(x@w3); 128x64 tile, wave=64x32 fused ----------------
__global__ __launch_bounds__(256, 3) void gemm1_kernel(
    const float* __restrict__ x, const float* __restrict__ w1g, const float* __restrict__ w3g,
    const int* __restrict__ tok_of_slot, const int* __restrict__ cnt,
    u16* __restrict__ act)
{
    int e = blockIdx.z;
    int count = cnt[e];
    int m0 = blockIdx.y * 128;
    if (m0 >= count) return;
    int n0 = blockIdx.x * 64;

    __shared__ u16 As[128 * 64];
    __shared__ u16 B1s[64 * 64];
    __shared__ u16 B3s[64 * 64];
    __shared__ int toks[128];

    int t = threadIdx.x;
    if (t < 128) {
        int s = m0 + t;
        toks[t] = (s < count) ? tok_of_slot[e * kCap + s] : -1;
    }

    int lane = t & 63;
    int wv = t >> 6;
    int wm = (wv >> 1) * 64;   // wave m-offset
    int wn = (wv & 1) * 32;    // wave n-offset
    int lr = lane & 15;
    int kg = lane >> 4;

    f32x4 accg[4][2], accu[4][2];
    #pragma unroll
    for (int i = 0; i < 4; ++i)
        #pragma unroll
        for (int j = 0; j < 2; ++j) {
            accg[i][j] = f32x4{0.f, 0.f, 0.f, 0.f};
            accu[i][j] = f32x4{0.f, 0.f, 0.f, 0.f};
        }

    const float* w1e = w1g + (size_t)e * kH * kI;
    const float* w3e = w3g + (size_t)e * kH * kI;

    for (int k0 = 0; k0 < kH; k0 += 64) {
        __syncthreads();
        // ---- stage A: gathered x rows, fp32->bf16, b128 writes ----
        #pragma unroll
        for (int r = 0; r < 4; ++r) {
            int f = r * 256 + t;
            int row = f >> 3, k8 = (f & 7) * 8;
            int tk = toks[row];
            float4 v0 = make_float4(0.f, 0.f, 0.f, 0.f), v1 = v0;
            if (tk >= 0) {
                const float* p = x + (size_t)tk * kH + k0 + k8;
                v0 = *(const float4*)p;
                v1 = *(const float4*)(p + 4);
            }
            uint4 w;
            w.x = pk2(v0.x, v0.y); w.y = pk2(v0.z, v0.w);
            w.z = pk2(v1.x, v1.y); w.w = pk2(v1.z, v1.w);
            *(uint4*)&As[swz(row, k8)] = w;
        }
        // ---- stage B1/B3: 4x4 register transpose, packed b64 writes ----
        {
            int bn = (t & 15) * 4, bk = (t >> 4) * 4;
            const float* p1 = w1e + (size_t)(k0 + bk) * kI + n0 + bn;
            float4 c0 = *(const float4*)p1;
            float4 c1 = *(const float4*)(p1 + kI);
            float4 c2 = *(const float4*)(p1 + 2 * kI);
            float4 c3 = *(const float4*)(p1 + 3 * kI);
            uint2 q;
            q.x = pk2(c0.x, c1.x); q.y = pk2(c2.x, c3.x); *(uint2*)&B1s[swz(bn + 0, bk)] = q;
            q.x = pk2(c0.y, c1.y); q.y = pk2(c2.y, c3.y); *(uint2*)&B1s[swz(bn + 1, bk)] = q;
            q.x = pk2(c0.z, c1.z); q.y = pk2(c2.z, c3.z); *(uint2*)&B1s[swz(bn + 2, bk)] = q;
            q.x = pk2(c0.w, c1.w); q.y = pk2(c2.w, c3.w); *(uint2*)&B1s[swz(bn + 3, bk)] = q;
            const float* p3 = w3e + (size_t)(k0 + bk) * kI + n0 + bn;
            c0 = *(const float4*)p3;
            c1 = *(const float4*)(p3 + kI);
            c2 = *(const float4*)(p3 + 2 * kI);
            c3 = *(const float4*)(p3 + 3 * kI);
            q.x = pk2(c0.x, c1.x); q.y = pk2(c2.x, c3.x); *(uint2*)&B3s[swz(bn + 0, bk)] = q;
            q.x = pk2(c0.y, c1.y); q.y = pk2(c2.y, c3.y); *(uint2*)&B3s[swz(bn + 1, bk)] = q;
            q.x = pk2(c0.z, c1.z); q.y = pk2(c2.z, c3.z); *(uint2*)&B3s[swz(bn + 2, bk)] = q;
            q.x = pk2(c0.w, c1.w); q.y = pk2(c2.w, c3.w); *(uint2*)&B3s[swz(bn + 3, bk)] = q;
        }
        __syncthreads();
        // ---- MFMA: a[4] x (b1,b3)[2] per k-half ----
        #pragma unroll
        for (int h = 0; h < 2; ++h) {
            int kk = h * 32 + kg * 8;
            bf16x8 a[4];
            #pragma unroll
            for (int i = 0; i < 4; ++i)
                a[i] = *(const bf16x8*)&As[swz(wm + i * 16 + lr, kk)];
            #pragma unroll
            for (int ni = 0; ni < 2; ++ni) {
                bf16x8 b1 = *(const bf16x8*)&B1s[swz(wn + ni * 16 + lr, kk)];
                bf16x8 b3 = *(const bf16x8*)&B3s[swz(wn + ni * 16 + lr, kk)];
                #pragma unroll
                for (int mi = 0; mi < 4; ++mi) {
                    accg[mi][ni] = __builtin_amdgcn_mfma_f32_16x16x32_bf16(a[mi], b1, accg[mi][ni], 0, 0, 0);
                    accu[mi][ni] = __builtin_amdgcn_mfma_f32_16x16x32_bf16(a[mi], b3, accu[mi][ni], 0, 0, 0);
                }
            }
        }
    }

    // epilogue: silu(g)*u -> bf16 act.  C/D: col=lane&15, row=(lane>>4)*4+reg
    u16* actp = act + (size_t)e * kCap * kI;
    #pragma unroll
    for (int mi = 0; mi < 4; ++mi)
        #pragma unroll
        for (int ni = 0; ni < 2; ++ni)
            #pragma unroll
            for (int j = 0; j < 4; ++j) {
                int srow = m0 + wm + mi * 16 + kg * 4 + j;
                int icol = n0 + wn + ni * 16 + lr;
                float g = accg[mi][ni][j], u = accu[mi][ni][j];
                float sg = g / (1.f + __expf(-g));
                actp[(size_t)srow * kI + icol] = f2bf(sg * u);
            }
}

// ---------------- GEMM2: y = act @ w2; out[tok] += w*y; 128x128 tile ----------------
__global__ __launch_bounds__(256, 3) void gemm2_kernel(
    const u16* __restrict__ act, const float* __restrict__ w2g,
    const int* __restrict__ tok_of_slot, const float* __restrict__ wt_of_slot,
    const int* __restrict__ cnt, float* __restrict__ out)
{
    int e = blockIdx.z;
    int count = cnt[e];
    int m0 = blockIdx.y * 128;
    if (m0 >= count) return;
    int n0 = blockIdx.x * 128;

    __shared__ u16 As[128 * 64];
    __shared__ u16 Bs[128 * 64];
    __shared__ int toks[128];
    __shared__ float wts[128];

    int t = threadIdx.x;
    if (t < 128) {
        int s = m0 + t;
        toks[t] = (s < count) ? tok_of_slot[e * kCap + s] : 0;
        wts[t]  = (s < count) ? wt_of_slot[e * kCap + s] : 0.f;
    }

    int lane = t & 63;
    int wv = t >> 6;
    int wm = (wv >> 1) * 64;
    int wn = (wv & 1) * 64;
    int lr = lane & 15;
    int kg = lane >> 4;

    f32x4 acc[4][4];
    #pragma unroll
    for (int i = 0; i < 4; ++i)
        #pragma unroll
        for (int j = 0; j < 4; ++j) acc[i][j] = f32x4{0.f, 0.f, 0.f, 0.f};

    const u16* ae = act + (size_t)e * kCap * kI;
    const float* w2e = w2g + (size_t)e * kI * kH;

    for (int k0 = 0; k0 < kI; k0 += 64) {
        __syncthreads();
        // ---- stage A: act already bf16, pure b128 copy ----
        #pragma unroll
        for (int r = 0; r < 4; ++r) {
            int f = r * 256 + t;
            int row = f >> 3, k8 = (f & 7) * 8;
            uint4 v = *(const uint4*)(ae + (size_t)(m0 + row) * kI + k0 + k8);
            *(uint4*)&As[swz(row, k8)] = v;
        }
        // ---- stage B: w2 4x4 register transpose ----
        #pragma unroll
        for (int r = 0; r < 2; ++r) {
            int f = r * 256 + t;
            int bn = (f & 31) * 4, bk = (f >> 5) * 4;
            const float* p = w2e + (size_t)(k0 + bk) * kH + n0 + bn;
            float4 c0 = *(const float4*)p;
            float4 c1 = *(const float4*)(p + kH);
            float4 c2 = *(const float4*)(p + 2 * kH);
            float4 c3 = *(const float4*)(p + 3 * kH);
            uint2 q;
            q.x = pk2(c0.x, c1.x); q.y = pk2(c2.x, c3.x); *(uint2*)&Bs[swz(bn + 0, bk)] = q;
            q.x = pk2(c0.y, c1.y); q.y = pk2(c2.y, c3.y); *(uint2*)&Bs[swz(bn + 1, bk)] = q;
            q.x = pk2(c0.z, c1.z); q.y = pk2(c2.z, c3.z); *(uint2*)&Bs[swz(bn + 2, bk)] = q;
            q.x = pk2(c0.w, c1.w); q.y = pk2(c2.w, c3.w); *(uint2*)&Bs[swz(bn + 3, bk)] = q;
        }
        __syncthreads();
        #pragma unroll
        for (int h = 0; h < 2; ++h) {
            int kk = h * 32 + kg * 8;
            bf16x8 a[4];
            #pragma unroll
            for (int i = 0; i < 4; ++i)
                a[i] = *(const bf16x8*)&As[swz(wm + i * 16 + lr, kk)];
            #pragma unroll
            for (int ni = 0; ni < 4; ++ni) {
                bf16x8 b = *(const bf16x8*)&Bs[swz(wn + ni * 16 + lr, kk)];
                #pragma unroll
                for (int mi = 0; mi < 4; ++mi)
                    acc[mi][ni] = __builtin_amdgcn_mfma_f32_16x16x32_bf16(a[mi], b, acc[mi][ni], 0, 0, 0);
            }
        }
    }

    #pragma unroll
    for (int mi = 0; mi < 4; ++mi)
        #pragma unroll
        for (int ni = 0; ni < 4; ++ni)
            #pragma unroll
            for (int j = 0; j < 4; ++j) {
                int sr = wm + mi * 16 + kg * 4 + j;
                if (m0 + sr < count) {
                    atomicAdd(&out[(size_t)toks[sr] * kH + n0 + wn + ni * 16 + lr],
                              wts[sr] * acc[mi][ni][j]);
                }
            }
}

extern "C" void kernel_launch(void* const* d_in, const int* in_sizes, int n_in,
                              void* d_out, int out_size, void* d_ws, size_t ws_size,
                              hipStream_t stream) {
    const float* x      = (const float*)d_in[0];
    const float* w_gate = (const float*)d_in[1];
    const float* gbias  = (const float*)d_in[2];
    const float* w1     = (const float*)d_in[3];
    const float* w3     = (const float*)d_in[4];
    const float* w2     = (const float*)d_in[5];
    float* out = (float*)d_out;

    int ntok = in_sizes[0] / kH;

    char* ws = (char*)d_ws;
    int*   cnt         = (int*)(ws);
    int*   tok_of_slot = (int*)(ws + 4096);
    float* wt_of_slot  = (float*)(ws + 4096 + kE * kCap * 4);
    u16*   act         = (u16*)(ws + 4096 + 2 * kE * kCap * 4);   // 64 MB

    hipMemsetAsync(cnt, 0, kE * sizeof(int), stream);
    hipMemsetAsync(d_out, 0, (size_t)out_size * sizeof(float), stream);

    gate_kernel<<<ntok, 256, 0, stream>>>(x, w_gate, gbias, cnt, tok_of_slot, wt_of_slot);

    dim3 g1(kI / 64, kCap / 128, kE);
    gemm1_kernel<<<g1, 256, 0, stream>>>(x, w1, w3, tok_of_slot, cnt, act);

    dim3 g2(kH / 128, kCap / 128, kE);
    gemm2_kernel<<<g2, 256, 0, stream>>>(act, w2, tok_of_slot, wt_of_slot, cnt, out);
}